// Round 6
// baseline (496.370 us; speedup 1.0000x reference)
//
#include <hip/hip_runtime.h>
#include <math.h>

#define NPTS 4096
#define BLK 64
#define V 64
#define NPROJ 256
#define NBATCH 32

// R6: one wave per block (BLK=64) -> NO __syncthreads anywhere; intra-wave
// LDS exchange ordered by compiler lgkmcnt. V=64 regs/thread/array.
// Layouts (element idx, 12 bits; T=thread 6b, c=chunk 4b, l=comp 2b):
//   A: T=idx[11:6], c=idx[5:2]                (regs = idx[5:0])
//   B: T={idx[11:10],idx[5:2]}, c=idx[9:6]    (regs = {idx[9:6],idx[1:0]})
//   C: T=idx[9:4],  c={idx[11:10],idx[3:2]}   (regs = {idx[11:10],idx[3:0]})
// float4-slot placement: A/B: slot=(T<<4)|(c^(T&15)); C: slot=(T<<4)|(c^(T>>2&15)).
// All write/read patterns verified bank-even (8 dwords/bank per b128) and
// bijective; cross-layout scatter formulas verified on concrete indices.
// Normalized bitonic: merges 2..64 in-reg; m128/m256 via shfl_xor (DPP);
// m512..m4096 via LDS with reversal fused into the layout-entry read.

__device__ __forceinline__ void cmpex_asc(float& a, float& b) {
    const float lo = fminf(a, b), hi = fmaxf(a, b);
    a = lo; b = hi;
}

template<int JB, int JL>
__device__ __forceinline__ void stages(float* v) {
#pragma unroll
    for (int r = 0; r < V; ++r)
        if ((r & JB) == 0) cmpex_asc(v[r], v[r | JB]);
    if constexpr (JB > JL) stages<(JB >> 1), JL>(v);
}

template<int MASK>
__device__ __forceinline__ void rev_inreg(float* v) {
    constexpr int S = (MASK + 1) >> 1;
#pragma unroll
    for (int r = 0; r < V; ++r) {
        if ((r & S) == 0) {
            const float a = v[r], b = v[r ^ MASK];
            v[r] = fminf(a, b);
            v[r ^ MASK] = fmaxf(a, b);
        }
    }
}

// Reversal across thread-pair (xor XM), registers reversed (r <-> 63-r).
template<int XM>
__device__ __forceinline__ void rev_shfl(float* v, bool hi) {
#pragma unroll
    for (int r = 0; r < 32; ++r) {
        const float pa = __shfl_xor(v[63 - r], XM, 64);
        const float pb = __shfl_xor(v[r], XM, 64);
        v[r]      = hi ? fmaxf(v[r], pa)      : fminf(v[r], pa);
        v[63 - r] = hi ? fmaxf(v[63 - r], pb) : fminf(v[63 - r], pb);
    }
}
// Same-register cross-thread stage (xor XM).
template<int XM>
__device__ __forceinline__ void stage_shfl(float* v, bool hi) {
#pragma unroll
    for (int r = 0; r < V; ++r) {
        const float q = __shfl_xor(v[r], XM, 64);
        v[r] = hi ? fmaxf(v[r], q) : fminf(v[r], q);
    }
}

// A->B and B->A scatter-write (same formula, symmetric).
__device__ __forceinline__ void write_AB(float* s, const float* v, int sAB, int t15) {
    float4* s4 = (float4*)s;
#pragma unroll
    for (int c = 0; c < 16; ++c)
        s4[sAB | (c << 4) | (t15 ^ c)] =
            make_float4(v[4*c], v[4*c+1], v[4*c+2], v[4*c+3]);
}
// Own-slot read, valid for A- and B-resident phases.
__device__ __forceinline__ void read_own(const float* s, float* v, int t, int t15) {
    const float4* s4 = (const float4*)s;
#pragma unroll
    for (int c = 0; c < 16; ++c) {
        const float4 f = s4[(t << 4) | (c ^ t15)];
        v[4*c] = f.x; v[4*c+1] = f.y; v[4*c+2] = f.z; v[4*c+3] = f.w;
    }
}
// B-entry read fused with reversal: own + partner (t^PM, c^CM, comps
// reversed). Keep side: chunk bit KB, or thread-uniform thi when KB==0.
template<int PM, int CM, int KB>
__device__ __forceinline__ void read_rev_B(const float* s, float* v, int t, int t15, bool thi) {
    const float4* s4 = (const float4*)s;
    const int pt = t ^ PM, pt15 = t15 ^ (PM & 15);
#pragma unroll
    for (int c = 0; c < 16; ++c) {
        const float4 o = s4[(t << 4) | (c ^ t15)];
        const float4 q = s4[(pt << 4) | ((c ^ CM) ^ pt15)];
        const bool mx = KB ? ((c & KB) != 0) : thi;
        v[4*c+0] = mx ? fmaxf(o.x, q.w) : fminf(o.x, q.w);
        v[4*c+1] = mx ? fmaxf(o.y, q.z) : fminf(o.y, q.z);
        v[4*c+2] = mx ? fmaxf(o.z, q.y) : fminf(o.z, q.y);
        v[4*c+3] = mx ? fmaxf(o.w, q.x) : fminf(o.w, q.x);
    }
}
// A->C scatter-write.
__device__ __forceinline__ void write_AC(float* s, const float* v, int t15, int qAC) {
    float4* s4 = (float4*)s;
#pragma unroll
    for (int c = 0; c < 16; ++c)
        s4[(t15 << 6) | ((c >> 2) << 4) | (qAC ^ (c & 3))] =
            make_float4(v[4*c], v[4*c+1], v[4*c+2], v[4*c+3]);
}
// C-entry read fused with m4096 reversal (partner t^63, c^15, keep c&8).
__device__ __forceinline__ void read_rev_C(const float* s, float* v, int t, int th) {
    const float4* s4 = (const float4*)s;
    const int pt = t ^ 63, pth = th ^ 15;
#pragma unroll
    for (int c = 0; c < 16; ++c) {
        const float4 o = s4[(t << 4) | (c ^ th)];
        const float4 q = s4[(pt << 4) | ((c ^ 15) ^ pth)];
        const bool mx = (c & 8) != 0;
        v[4*c+0] = mx ? fmaxf(o.x, q.w) : fminf(o.x, q.w);
        v[4*c+1] = mx ? fmaxf(o.y, q.z) : fminf(o.y, q.z);
        v[4*c+2] = mx ? fmaxf(o.z, q.y) : fminf(o.z, q.y);
        v[4*c+3] = mx ? fmaxf(o.w, q.x) : fminf(o.w, q.x);
    }
}
// C->B scatter-write.
__device__ __forceinline__ void write_CB(float* s, const float* v, int sCB, int qCB) {
    float4* s4 = (float4*)s;
#pragma unroll
    for (int c = 0; c < 16; ++c)
        s4[((c >> 2) << 8) | sCB | ((c & 3) << 4) | (qCB ^ (c & 3))] =
            make_float4(v[4*c], v[4*c+1], v[4*c+2], v[4*c+3]);
}

// Full ascending sort of 4096 floats held as v[64] per thread (A layout).
__device__ __forceinline__ void sort4096(float* v, float* buf, int t) {
    const int t15 = t & 15;
    const int sAB = (t >> 4) << 8;
    const int qAC = ((t >> 4) << 2) ^ t15;
    const int th  = (t >> 2) & 15;
    const int sCB = (t & 3) << 6;
    const int qCB = (t >> 2) ^ ((t & 3) << 2);
    const bool hi1  = (t & 1) != 0;
    const bool hi2  = (t & 2) != 0;
    const bool hi16 = (t & 16) != 0;

    // merges 2..64: fully in-register
    rev_inreg<1>(v);
    rev_inreg<3>(v);  stages<1, 1>(v);
    rev_inreg<7>(v);  stages<2, 1>(v);
    rev_inreg<15>(v); stages<4, 1>(v);
    rev_inreg<31>(v); stages<8, 1>(v);
    rev_inreg<63>(v); stages<16, 1>(v);

    // merge 128: rev across t^1 (DPP), cleaners in-reg
    rev_shfl<1>(v, hi1);
    stages<32, 1>(v);

    // merge 256: rev t^3, j=128 (t^2), j=64 (t^1), cleaners in-reg
    rev_shfl<3>(v, hi2);
    stage_shfl<2>(v, hi2);
    stage_shfl<1>(v, hi1);
    stages<32, 1>(v);

    // merge 512: rev in B (PM=15, CM=7, keep c&4); j=128,64; back to A
    write_AB(buf, v, sAB, t15);
    read_rev_B<15, 7, 4>(buf, v, t, t15, false);
    stages<8, 4>(v);
    write_AB(buf, v, sAB, t15);
    read_own(buf, v, t, t15);
    stages<32, 1>(v);

    // merge 1024: rev in B (PM=15, CM=15, keep c&8); j=256,128,64
    write_AB(buf, v, sAB, t15);
    read_rev_B<15, 15, 8>(buf, v, t, t15, false);
    stages<16, 4>(v);
    write_AB(buf, v, sAB, t15);
    read_own(buf, v, t, t15);
    stages<32, 1>(v);

    // merge 2048: rev in B (PM=31, CM=15, keep t&16); j=512..64
    write_AB(buf, v, sAB, t15);
    read_rev_B<31, 15, 0>(buf, v, t, t15, hi16);
    stages<32, 4>(v);
    write_AB(buf, v, sAB, t15);
    read_own(buf, v, t, t15);
    stages<32, 1>(v);

    // merge 4096: rev in C (keep c&8); j=1024 in C; C->B j=512..64; B->A
    write_AC(buf, v, t15, qAC);
    read_rev_C(buf, v, t, th);
    stages<16, 16>(v);
    write_CB(buf, v, sCB, qCB);
    read_own(buf, v, t, t15);
    stages<32, 4>(v);
    write_AB(buf, v, sAB, t15);
    read_own(buf, v, t, t15);
    stages<32, 1>(v);
}

__device__ __forceinline__ void load_project(const float* base, float* v,
                                             float p0, float p1, float p2) {
    const float4* b4 = (const float4*)base;
#pragma unroll
    for (int g = 0; g < 16; ++g) {
        float4 a = b4[g * 3 + 0], c = b4[g * 3 + 1], d = b4[g * 3 + 2];
        v[4*g+0] = a.x * p0 + a.y * p1 + a.z * p2;
        v[4*g+1] = a.w * p0 + c.x * p1 + c.y * p2;
        v[4*g+2] = c.z * p0 + c.w * p1 + d.x * p2;
        v[4*g+3] = d.y * p0 + d.z * p1 + d.w * p2;
    }
}

__global__ __launch_bounds__(BLK, 3) void swd_kernel(
    const float* __restrict__ x, const float* __restrict__ y,
    const float* __restrict__ theta, const float* __restrict__ rot,
    float* __restrict__ per_batch) {
    __shared__ float buf[NPTS];

    const int t = threadIdx.x;   // 0..63, one wave
    const int p = blockIdx.x;
    const int b = blockIdx.y;

    const float t0 = theta[p * 3 + 0], t1 = theta[p * 3 + 1], t2 = theta[p * 3 + 2];
    const float* R = rot + b * 9;
    const float p0 = t0 * R[0] + t1 * R[3] + t2 * R[6];
    const float p1 = t0 * R[1] + t1 * R[4] + t2 * R[7];
    const float p2 = t0 * R[2] + t1 * R[5] + t2 * R[8];

    // Sort x (sorted result stays in sx registers).
    float sx[V];
    load_project(x + (size_t)b * NPTS * 3 + (size_t)t * V * 3, sx, p0, p1, p2);
    sort4096(sx, buf, t);

    // Sort y (reuses the same LDS buffer; ordering via lgkmcnt, same wave).
    float vy[V];
    load_project(y + (size_t)b * NPTS * 3 + (size_t)t * V * 3, vy, p0, p1, p2);
    sort4096(vy, buf, t);

    // Sum squared differences of sorted sequences.
    float s = 0.0f;
#pragma unroll
    for (int r = 0; r < V; ++r) {
        const float d = sx[r] - vy[r];
        s += d * d;
    }
    for (int off = 32; off > 0; off >>= 1) s += __shfl_down(s, off, 64);
    if (t == 0) atomicAdd(&per_batch[b], s);
}

__global__ void finalize_kernel(const float* __restrict__ per_batch, float* __restrict__ out) {
    const int t = threadIdx.x;  // 64 threads
    float v = (t < NBATCH) ? sqrtf(per_batch[t] * (1.0f / (float)NPROJ)) : 0.0f;
    for (int off = 32; off > 0; off >>= 1) v += __shfl_down(v, off, 64);
    if (t == 0) out[0] = v * (1.0f / (float)NBATCH);
}

extern "C" void kernel_launch(void* const* d_in, const int* in_sizes, int n_in,
                              void* d_out, int out_size, void* d_ws, size_t ws_size,
                              hipStream_t stream) {
    const float* x = (const float*)d_in[0];
    const float* y = (const float*)d_in[1];
    const float* theta = (const float*)d_in[2];
    const float* rot = (const float*)d_in[3];
    float* per_batch = (float*)d_ws;
    float* out = (float*)d_out;

    hipMemsetAsync(per_batch, 0, NBATCH * sizeof(float), stream);

    dim3 grid(NPROJ, NBATCH);
    swd_kernel<<<grid, BLK, 0, stream>>>(x, y, theta, rot, per_batch);

    finalize_kernel<<<1, 64, 0, stream>>>(per_batch, out);
}

// Round 7
// 398.578 us; speedup vs baseline: 1.2454x; 1.2454x over previous
//
#include <hip/hip_runtime.h>
#include <math.h>

#define NPTS 4096
#define BLK 64
#define V 64
#define NPROJ 256
#define NBATCH 32

// R7 = R6 + __launch_bounds__(64,2): one wave per block, no __syncthreads;
// the (64,3) bound capped VGPRs at ~168 which forced the compiler to spill
// sx[64] to scratch (rocprof: WRITE_SIZE 340 MB). (64,2) -> ~256 VGPR cap,
// sx+vy+temps (~170) fit, zero spills, ~8 waves/CU.
// Layouts (element idx, 12 bits; T=thread 6b, c=chunk 4b, l=comp 2b):
//   A: T=idx[11:6], c=idx[5:2]                (regs = idx[5:0])
//   B: T={idx[11:10],idx[5:2]}, c=idx[9:6]    (regs = {idx[9:6],idx[1:0]})
//   C: T=idx[9:4],  c={idx[11:10],idx[3:2]}   (regs = {idx[11:10],idx[3:0]})
// float4-slot placement: A/B: slot=(T<<4)|(c^(T&15)); C: slot=(T<<4)|(c^(T>>2&15)).
// All patterns bank-even (8 dwords/bank per b128) and bijective (verified).
// Normalized bitonic: merges 2..64 in-reg; m128/m256 via shfl_xor (DPP);
// m512..m4096 via LDS with reversal fused into the layout-entry read.

__device__ __forceinline__ void cmpex_asc(float& a, float& b) {
    const float lo = fminf(a, b), hi = fmaxf(a, b);
    a = lo; b = hi;
}

template<int JB, int JL>
__device__ __forceinline__ void stages(float* v) {
#pragma unroll
    for (int r = 0; r < V; ++r)
        if ((r & JB) == 0) cmpex_asc(v[r], v[r | JB]);
    if constexpr (JB > JL) stages<(JB >> 1), JL>(v);
}

template<int MASK>
__device__ __forceinline__ void rev_inreg(float* v) {
    constexpr int S = (MASK + 1) >> 1;
#pragma unroll
    for (int r = 0; r < V; ++r) {
        if ((r & S) == 0) {
            const float a = v[r], b = v[r ^ MASK];
            v[r] = fminf(a, b);
            v[r ^ MASK] = fmaxf(a, b);
        }
    }
}

// Reversal across thread-pair (xor XM), registers reversed (r <-> 63-r).
template<int XM>
__device__ __forceinline__ void rev_shfl(float* v, bool hi) {
#pragma unroll
    for (int r = 0; r < 32; ++r) {
        const float pa = __shfl_xor(v[63 - r], XM, 64);
        const float pb = __shfl_xor(v[r], XM, 64);
        v[r]      = hi ? fmaxf(v[r], pa)      : fminf(v[r], pa);
        v[63 - r] = hi ? fmaxf(v[63 - r], pb) : fminf(v[63 - r], pb);
    }
}
// Same-register cross-thread stage (xor XM).
template<int XM>
__device__ __forceinline__ void stage_shfl(float* v, bool hi) {
#pragma unroll
    for (int r = 0; r < V; ++r) {
        const float q = __shfl_xor(v[r], XM, 64);
        v[r] = hi ? fmaxf(v[r], q) : fminf(v[r], q);
    }
}

// A->B and B->A scatter-write (same formula, symmetric).
__device__ __forceinline__ void write_AB(float* s, const float* v, int sAB, int t15) {
    float4* s4 = (float4*)s;
#pragma unroll
    for (int c = 0; c < 16; ++c)
        s4[sAB | (c << 4) | (t15 ^ c)] =
            make_float4(v[4*c], v[4*c+1], v[4*c+2], v[4*c+3]);
}
// Own-slot read, valid for A- and B-resident phases.
__device__ __forceinline__ void read_own(const float* s, float* v, int t, int t15) {
    const float4* s4 = (const float4*)s;
#pragma unroll
    for (int c = 0; c < 16; ++c) {
        const float4 f = s4[(t << 4) | (c ^ t15)];
        v[4*c] = f.x; v[4*c+1] = f.y; v[4*c+2] = f.z; v[4*c+3] = f.w;
    }
}
// B-entry read fused with reversal: own + partner (t^PM, c^CM, comps
// reversed). Keep side: chunk bit KB, or thread-uniform thi when KB==0.
template<int PM, int CM, int KB>
__device__ __forceinline__ void read_rev_B(const float* s, float* v, int t, int t15, bool thi) {
    const float4* s4 = (const float4*)s;
    const int pt = t ^ PM, pt15 = t15 ^ (PM & 15);
#pragma unroll
    for (int c = 0; c < 16; ++c) {
        const float4 o = s4[(t << 4) | (c ^ t15)];
        const float4 q = s4[(pt << 4) | ((c ^ CM) ^ pt15)];
        const bool mx = KB ? ((c & KB) != 0) : thi;
        v[4*c+0] = mx ? fmaxf(o.x, q.w) : fminf(o.x, q.w);
        v[4*c+1] = mx ? fmaxf(o.y, q.z) : fminf(o.y, q.z);
        v[4*c+2] = mx ? fmaxf(o.z, q.y) : fminf(o.z, q.y);
        v[4*c+3] = mx ? fmaxf(o.w, q.x) : fminf(o.w, q.x);
    }
}
// A->C scatter-write.
__device__ __forceinline__ void write_AC(float* s, const float* v, int t15, int qAC) {
    float4* s4 = (float4*)s;
#pragma unroll
    for (int c = 0; c < 16; ++c)
        s4[(t15 << 6) | ((c >> 2) << 4) | (qAC ^ (c & 3))] =
            make_float4(v[4*c], v[4*c+1], v[4*c+2], v[4*c+3]);
}
// C-entry read fused with m4096 reversal (partner t^63, c^15, keep c&8).
__device__ __forceinline__ void read_rev_C(const float* s, float* v, int t, int th) {
    const float4* s4 = (const float4*)s;
    const int pt = t ^ 63, pth = th ^ 15;
#pragma unroll
    for (int c = 0; c < 16; ++c) {
        const float4 o = s4[(t << 4) | (c ^ th)];
        const float4 q = s4[(pt << 4) | ((c ^ 15) ^ pth)];
        const bool mx = (c & 8) != 0;
        v[4*c+0] = mx ? fmaxf(o.x, q.w) : fminf(o.x, q.w);
        v[4*c+1] = mx ? fmaxf(o.y, q.z) : fminf(o.y, q.z);
        v[4*c+2] = mx ? fmaxf(o.z, q.y) : fminf(o.z, q.y);
        v[4*c+3] = mx ? fmaxf(o.w, q.x) : fminf(o.w, q.x);
    }
}
// C->B scatter-write.
__device__ __forceinline__ void write_CB(float* s, const float* v, int sCB, int qCB) {
    float4* s4 = (float4*)s;
#pragma unroll
    for (int c = 0; c < 16; ++c)
        s4[((c >> 2) << 8) | sCB | ((c & 3) << 4) | (qCB ^ (c & 3))] =
            make_float4(v[4*c], v[4*c+1], v[4*c+2], v[4*c+3]);
}

// Full ascending sort of 4096 floats held as v[64] per thread (A layout).
__device__ __forceinline__ void sort4096(float* v, float* buf, int t) {
    const int t15 = t & 15;
    const int sAB = (t >> 4) << 8;
    const int qAC = ((t >> 4) << 2) ^ t15;
    const int th  = (t >> 2) & 15;
    const int sCB = (t & 3) << 6;
    const int qCB = (t >> 2) ^ ((t & 3) << 2);
    const bool hi1  = (t & 1) != 0;
    const bool hi2  = (t & 2) != 0;
    const bool hi16 = (t & 16) != 0;

    // merges 2..64: fully in-register
    rev_inreg<1>(v);
    rev_inreg<3>(v);  stages<1, 1>(v);
    rev_inreg<7>(v);  stages<2, 1>(v);
    rev_inreg<15>(v); stages<4, 1>(v);
    rev_inreg<31>(v); stages<8, 1>(v);
    rev_inreg<63>(v); stages<16, 1>(v);

    // merge 128: rev across t^1 (DPP), cleaners in-reg
    rev_shfl<1>(v, hi1);
    stages<32, 1>(v);

    // merge 256: rev t^3, j=128 (t^2), j=64 (t^1), cleaners in-reg
    rev_shfl<3>(v, hi2);
    stage_shfl<2>(v, hi2);
    stage_shfl<1>(v, hi1);
    stages<32, 1>(v);

    // merge 512: rev in B (PM=15, CM=7, keep c&4); j=128,64; back to A
    write_AB(buf, v, sAB, t15);
    read_rev_B<15, 7, 4>(buf, v, t, t15, false);
    stages<8, 4>(v);
    write_AB(buf, v, sAB, t15);
    read_own(buf, v, t, t15);
    stages<32, 1>(v);

    // merge 1024: rev in B (PM=15, CM=15, keep c&8); j=256,128,64
    write_AB(buf, v, sAB, t15);
    read_rev_B<15, 15, 8>(buf, v, t, t15, false);
    stages<16, 4>(v);
    write_AB(buf, v, sAB, t15);
    read_own(buf, v, t, t15);
    stages<32, 1>(v);

    // merge 2048: rev in B (PM=31, CM=15, keep t&16); j=512..64
    write_AB(buf, v, sAB, t15);
    read_rev_B<31, 15, 0>(buf, v, t, t15, hi16);
    stages<32, 4>(v);
    write_AB(buf, v, sAB, t15);
    read_own(buf, v, t, t15);
    stages<32, 1>(v);

    // merge 4096: rev in C (keep c&8); j=1024 in C; C->B j=512..64; B->A
    write_AC(buf, v, t15, qAC);
    read_rev_C(buf, v, t, th);
    stages<16, 16>(v);
    write_CB(buf, v, sCB, qCB);
    read_own(buf, v, t, t15);
    stages<32, 4>(v);
    write_AB(buf, v, sAB, t15);
    read_own(buf, v, t, t15);
    stages<32, 1>(v);
}

__device__ __forceinline__ void load_project(const float* base, float* v,
                                             float p0, float p1, float p2) {
    const float4* b4 = (const float4*)base;
#pragma unroll
    for (int g = 0; g < 16; ++g) {
        float4 a = b4[g * 3 + 0], c = b4[g * 3 + 1], d = b4[g * 3 + 2];
        v[4*g+0] = a.x * p0 + a.y * p1 + a.z * p2;
        v[4*g+1] = a.w * p0 + c.x * p1 + c.y * p2;
        v[4*g+2] = c.z * p0 + c.w * p1 + d.x * p2;
        v[4*g+3] = d.y * p0 + d.z * p1 + d.w * p2;
    }
}

__global__ __launch_bounds__(BLK, 2) void swd_kernel(
    const float* __restrict__ x, const float* __restrict__ y,
    const float* __restrict__ theta, const float* __restrict__ rot,
    float* __restrict__ per_batch) {
    __shared__ float buf[NPTS];

    const int t = threadIdx.x;   // 0..63, one wave
    const int p = blockIdx.x;
    const int b = blockIdx.y;

    const float t0 = theta[p * 3 + 0], t1 = theta[p * 3 + 1], t2 = theta[p * 3 + 2];
    const float* R = rot + b * 9;
    const float p0 = t0 * R[0] + t1 * R[3] + t2 * R[6];
    const float p1 = t0 * R[1] + t1 * R[4] + t2 * R[7];
    const float p2 = t0 * R[2] + t1 * R[5] + t2 * R[8];

    // Sort x (sorted result stays in sx registers).
    float sx[V];
    load_project(x + (size_t)b * NPTS * 3 + (size_t)t * V * 3, sx, p0, p1, p2);
    sort4096(sx, buf, t);

    // Sort y (reuses the same LDS buffer; ordering via lgkmcnt, same wave).
    float vy[V];
    load_project(y + (size_t)b * NPTS * 3 + (size_t)t * V * 3, vy, p0, p1, p2);
    sort4096(vy, buf, t);

    // Sum squared differences of sorted sequences.
    float s = 0.0f;
#pragma unroll
    for (int r = 0; r < V; ++r) {
        const float d = sx[r] - vy[r];
        s += d * d;
    }
    for (int off = 32; off > 0; off >>= 1) s += __shfl_down(s, off, 64);
    if (t == 0) atomicAdd(&per_batch[b], s);
}

__global__ void finalize_kernel(const float* __restrict__ per_batch, float* __restrict__ out) {
    const int t = threadIdx.x;  // 64 threads
    float v = (t < NBATCH) ? sqrtf(per_batch[t] * (1.0f / (float)NPROJ)) : 0.0f;
    for (int off = 32; off > 0; off >>= 1) v += __shfl_down(v, off, 64);
    if (t == 0) out[0] = v * (1.0f / (float)NBATCH);
}

extern "C" void kernel_launch(void* const* d_in, const int* in_sizes, int n_in,
                              void* d_out, int out_size, void* d_ws, size_t ws_size,
                              hipStream_t stream) {
    const float* x = (const float*)d_in[0];
    const float* y = (const float*)d_in[1];
    const float* theta = (const float*)d_in[2];
    const float* rot = (const float*)d_in[3];
    float* per_batch = (float*)d_ws;
    float* out = (float*)d_out;

    hipMemsetAsync(per_batch, 0, NBATCH * sizeof(float), stream);

    dim3 grid(NPROJ, NBATCH);
    swd_kernel<<<grid, BLK, 0, stream>>>(x, y, theta, rot, per_batch);

    finalize_kernel<<<1, 64, 0, stream>>>(per_batch, out);
}

// Round 8
// 372.723 us; speedup vs baseline: 1.3317x; 1.0694x over previous
//
#include <hip/hip_runtime.h>
#include <math.h>

#define NPTS 4096
#define BLK 128
#define V 64
#define NPROJ 256
#define NBATCH 32

// R8: two waves per block — wave 0 sorts x, wave 1 sorts y, each with its own
// private 4096-float LDS buffer and NO barriers inside the sort (intra-wave
// lgkmcnt ordering). This caps per-thread live registers at v[64]+temps
// (~100), eliminating the R6/R7 spills (VGPR allocator refused >128).
// One __syncthreads after both sorts; wave 1 publishes sorted y, wave 0 diffs.
// Layouts (element idx, 12 bits; T=wave-lane 6b, c=chunk 4b, l=comp 2b):
//   A: T=idx[11:6], c=idx[5:2]                (regs = idx[5:0])
//   B: T={idx[11:10],idx[5:2]}, c=idx[9:6]    (regs = {idx[9:6],idx[1:0]})
//   C: T=idx[9:4],  c={idx[11:10],idx[3:2]}   (regs = {idx[11:10],idx[3:0]})
// float4-slot placement: A/B: slot=(T<<4)|(c^(T&15)); C: slot=(T<<4)|(c^(T>>2&15)).
// All patterns bank-even (8 dwords/bank per b128) and bijective (verified).
// Normalized bitonic: merges 2..64 in-reg; m128/m256 via shfl_xor (DPP);
// m512..m4096 via LDS with reversal fused into the layout-entry read.

__device__ __forceinline__ void cmpex_asc(float& a, float& b) {
    const float lo = fminf(a, b), hi = fmaxf(a, b);
    a = lo; b = hi;
}

template<int JB, int JL>
__device__ __forceinline__ void stages(float* v) {
#pragma unroll
    for (int r = 0; r < V; ++r)
        if ((r & JB) == 0) cmpex_asc(v[r], v[r | JB]);
    if constexpr (JB > JL) stages<(JB >> 1), JL>(v);
}

template<int MASK>
__device__ __forceinline__ void rev_inreg(float* v) {
    constexpr int S = (MASK + 1) >> 1;
#pragma unroll
    for (int r = 0; r < V; ++r) {
        if ((r & S) == 0) {
            const float a = v[r], b = v[r ^ MASK];
            v[r] = fminf(a, b);
            v[r ^ MASK] = fmaxf(a, b);
        }
    }
}

// Reversal across thread-pair (xor XM), registers reversed (r <-> 63-r).
template<int XM>
__device__ __forceinline__ void rev_shfl(float* v, bool hi) {
#pragma unroll
    for (int r = 0; r < 32; ++r) {
        const float pa = __shfl_xor(v[63 - r], XM, 64);
        const float pb = __shfl_xor(v[r], XM, 64);
        v[r]      = hi ? fmaxf(v[r], pa)      : fminf(v[r], pa);
        v[63 - r] = hi ? fmaxf(v[63 - r], pb) : fminf(v[63 - r], pb);
    }
}
// Same-register cross-thread stage (xor XM).
template<int XM>
__device__ __forceinline__ void stage_shfl(float* v, bool hi) {
#pragma unroll
    for (int r = 0; r < V; ++r) {
        const float q = __shfl_xor(v[r], XM, 64);
        v[r] = hi ? fmaxf(v[r], q) : fminf(v[r], q);
    }
}

// A->B and B->A scatter-write (same formula, symmetric).
__device__ __forceinline__ void write_AB(float* s, const float* v, int sAB, int t15) {
    float4* s4 = (float4*)s;
#pragma unroll
    for (int c = 0; c < 16; ++c)
        s4[sAB | (c << 4) | (t15 ^ c)] =
            make_float4(v[4*c], v[4*c+1], v[4*c+2], v[4*c+3]);
}
// Natural (own-slot) write, A/B-resident layout.
__device__ __forceinline__ void write_own(float* s, const float* v, int t, int t15) {
    float4* s4 = (float4*)s;
#pragma unroll
    for (int c = 0; c < 16; ++c)
        s4[(t << 4) | (c ^ t15)] =
            make_float4(v[4*c], v[4*c+1], v[4*c+2], v[4*c+3]);
}
// Own-slot read, valid for A- and B-resident phases.
__device__ __forceinline__ void read_own(const float* s, float* v, int t, int t15) {
    const float4* s4 = (const float4*)s;
#pragma unroll
    for (int c = 0; c < 16; ++c) {
        const float4 f = s4[(t << 4) | (c ^ t15)];
        v[4*c] = f.x; v[4*c+1] = f.y; v[4*c+2] = f.z; v[4*c+3] = f.w;
    }
}
// B-entry read fused with reversal: own + partner (t^PM, c^CM, comps
// reversed). Keep side: chunk bit KB, or thread-uniform thi when KB==0.
template<int PM, int CM, int KB>
__device__ __forceinline__ void read_rev_B(const float* s, float* v, int t, int t15, bool thi) {
    const float4* s4 = (const float4*)s;
    const int pt = t ^ PM, pt15 = t15 ^ (PM & 15);
#pragma unroll
    for (int c = 0; c < 16; ++c) {
        const float4 o = s4[(t << 4) | (c ^ t15)];
        const float4 q = s4[(pt << 4) | ((c ^ CM) ^ pt15)];
        const bool mx = KB ? ((c & KB) != 0) : thi;
        v[4*c+0] = mx ? fmaxf(o.x, q.w) : fminf(o.x, q.w);
        v[4*c+1] = mx ? fmaxf(o.y, q.z) : fminf(o.y, q.z);
        v[4*c+2] = mx ? fmaxf(o.z, q.y) : fminf(o.z, q.y);
        v[4*c+3] = mx ? fmaxf(o.w, q.x) : fminf(o.w, q.x);
    }
}
// A->C scatter-write.
__device__ __forceinline__ void write_AC(float* s, const float* v, int t15, int qAC) {
    float4* s4 = (float4*)s;
#pragma unroll
    for (int c = 0; c < 16; ++c)
        s4[(t15 << 6) | ((c >> 2) << 4) | (qAC ^ (c & 3))] =
            make_float4(v[4*c], v[4*c+1], v[4*c+2], v[4*c+3]);
}
// C-entry read fused with m4096 reversal (partner t^63, c^15, keep c&8).
__device__ __forceinline__ void read_rev_C(const float* s, float* v, int t, int th) {
    const float4* s4 = (const float4*)s;
    const int pt = t ^ 63, pth = th ^ 15;
#pragma unroll
    for (int c = 0; c < 16; ++c) {
        const float4 o = s4[(t << 4) | (c ^ th)];
        const float4 q = s4[(pt << 4) | ((c ^ 15) ^ pth)];
        const bool mx = (c & 8) != 0;
        v[4*c+0] = mx ? fmaxf(o.x, q.w) : fminf(o.x, q.w);
        v[4*c+1] = mx ? fmaxf(o.y, q.z) : fminf(o.y, q.z);
        v[4*c+2] = mx ? fmaxf(o.z, q.y) : fminf(o.z, q.y);
        v[4*c+3] = mx ? fmaxf(o.w, q.x) : fminf(o.w, q.x);
    }
}
// C->B scatter-write.
__device__ __forceinline__ void write_CB(float* s, const float* v, int sCB, int qCB) {
    float4* s4 = (float4*)s;
#pragma unroll
    for (int c = 0; c < 16; ++c)
        s4[((c >> 2) << 8) | sCB | ((c & 3) << 4) | (qCB ^ (c & 3))] =
            make_float4(v[4*c], v[4*c+1], v[4*c+2], v[4*c+3]);
}

// Full ascending sort of 4096 floats held as v[64] per thread (A layout).
// Single-wave: no barriers; LDS ordering via compiler lgkmcnt.
__device__ __forceinline__ void sort4096(float* v, float* buf, int t) {
    const int t15 = t & 15;
    const int sAB = (t >> 4) << 8;
    const int qAC = ((t >> 4) << 2) ^ t15;
    const int th  = (t >> 2) & 15;
    const int sCB = (t & 3) << 6;
    const int qCB = (t >> 2) ^ ((t & 3) << 2);
    const bool hi1  = (t & 1) != 0;
    const bool hi2  = (t & 2) != 0;
    const bool hi16 = (t & 16) != 0;

    // merges 2..64: fully in-register
    rev_inreg<1>(v);
    rev_inreg<3>(v);  stages<1, 1>(v);
    rev_inreg<7>(v);  stages<2, 1>(v);
    rev_inreg<15>(v); stages<4, 1>(v);
    rev_inreg<31>(v); stages<8, 1>(v);
    rev_inreg<63>(v); stages<16, 1>(v);

    // merge 128: rev across t^1 (DPP), cleaners in-reg
    rev_shfl<1>(v, hi1);
    stages<32, 1>(v);

    // merge 256: rev t^3, j=128 (t^2), j=64 (t^1), cleaners in-reg
    rev_shfl<3>(v, hi2);
    stage_shfl<2>(v, hi2);
    stage_shfl<1>(v, hi1);
    stages<32, 1>(v);

    // merge 512: rev in B (PM=15, CM=7, keep c&4); j=128,64; back to A
    write_AB(buf, v, sAB, t15);
    read_rev_B<15, 7, 4>(buf, v, t, t15, false);
    stages<8, 4>(v);
    write_AB(buf, v, sAB, t15);
    read_own(buf, v, t, t15);
    stages<32, 1>(v);

    // merge 1024: rev in B (PM=15, CM=15, keep c&8); j=256,128,64
    write_AB(buf, v, sAB, t15);
    read_rev_B<15, 15, 8>(buf, v, t, t15, false);
    stages<16, 4>(v);
    write_AB(buf, v, sAB, t15);
    read_own(buf, v, t, t15);
    stages<32, 1>(v);

    // merge 2048: rev in B (PM=31, CM=15, keep t&16); j=512..64
    write_AB(buf, v, sAB, t15);
    read_rev_B<31, 15, 0>(buf, v, t, t15, hi16);
    stages<32, 4>(v);
    write_AB(buf, v, sAB, t15);
    read_own(buf, v, t, t15);
    stages<32, 1>(v);

    // merge 4096: rev in C (keep c&8); j=1024 in C; C->B j=512..64; B->A
    write_AC(buf, v, t15, qAC);
    read_rev_C(buf, v, t, th);
    stages<16, 16>(v);
    write_CB(buf, v, sCB, qCB);
    read_own(buf, v, t, t15);
    stages<32, 4>(v);
    write_AB(buf, v, sAB, t15);
    read_own(buf, v, t, t15);
    stages<32, 1>(v);
}

__device__ __forceinline__ void load_project(const float* base, float* v,
                                             float p0, float p1, float p2) {
    const float4* b4 = (const float4*)base;
#pragma unroll
    for (int g = 0; g < 16; ++g) {
        float4 a = b4[g * 3 + 0], c = b4[g * 3 + 1], d = b4[g * 3 + 2];
        v[4*g+0] = a.x * p0 + a.y * p1 + a.z * p2;
        v[4*g+1] = a.w * p0 + c.x * p1 + c.y * p2;
        v[4*g+2] = c.z * p0 + c.w * p1 + d.x * p2;
        v[4*g+3] = d.y * p0 + d.z * p1 + d.w * p2;
    }
}

__global__ __launch_bounds__(BLK, 2) void swd_kernel(
    const float* __restrict__ x, const float* __restrict__ y,
    const float* __restrict__ theta, const float* __restrict__ rot,
    float* __restrict__ per_batch) {
    __shared__ float buf2[2][NPTS];

    const int t = threadIdx.x & 63;       // wave lane
    const int wave = threadIdx.x >> 6;    // 0: x, 1: y
    const int p = blockIdx.x;
    const int b = blockIdx.y;

    const float t0 = theta[p * 3 + 0], t1 = theta[p * 3 + 1], t2 = theta[p * 3 + 2];
    const float* R = rot + b * 9;
    const float p0 = t0 * R[0] + t1 * R[3] + t2 * R[6];
    const float p1 = t0 * R[1] + t1 * R[4] + t2 * R[7];
    const float p2 = t0 * R[2] + t1 * R[5] + t2 * R[8];

    float* buf = buf2[wave];
    const float* src = wave ? y : x;

    // Each wave sorts its own array, barrier-free.
    float v[V];
    load_project(src + (size_t)b * NPTS * 3 + (size_t)t * V * 3, v, p0, p1, p2);
    sort4096(v, buf, t);

    const int t15 = t & 15;
    // Wave 1 publishes sorted y in natural A slots; wave 0 then diffs.
    if (wave == 1) write_own(buf2[1], v, t, t15);
    __syncthreads();

    if (wave == 0) {
        float w[V];
        read_own(buf2[1], w, t, t15);
        float s = 0.0f;
#pragma unroll
        for (int r = 0; r < V; ++r) {
            const float d = v[r] - w[r];
            s += d * d;
        }
        for (int off = 32; off > 0; off >>= 1) s += __shfl_down(s, off, 64);
        if (t == 0) atomicAdd(&per_batch[b], s);
    }
}

__global__ void finalize_kernel(const float* __restrict__ per_batch, float* __restrict__ out) {
    const int t = threadIdx.x;  // 64 threads
    float v = (t < NBATCH) ? sqrtf(per_batch[t] * (1.0f / (float)NPROJ)) : 0.0f;
    for (int off = 32; off > 0; off >>= 1) v += __shfl_down(v, off, 64);
    if (t == 0) out[0] = v * (1.0f / (float)NBATCH);
}

extern "C" void kernel_launch(void* const* d_in, const int* in_sizes, int n_in,
                              void* d_out, int out_size, void* d_ws, size_t ws_size,
                              hipStream_t stream) {
    const float* x = (const float*)d_in[0];
    const float* y = (const float*)d_in[1];
    const float* theta = (const float*)d_in[2];
    const float* rot = (const float*)d_in[3];
    float* per_batch = (float*)d_ws;
    float* out = (float*)d_out;

    hipMemsetAsync(per_batch, 0, NBATCH * sizeof(float), stream);

    dim3 grid(NPROJ, NBATCH);
    swd_kernel<<<grid, BLK, 0, stream>>>(x, y, theta, rot, per_batch);

    finalize_kernel<<<1, 64, 0, stream>>>(per_batch, out);
}